// Round 8
// baseline (236.502 us; speedup 1.0000x reference)
//
#include <hip/hip_runtime.h>

#define HH 256
#define WW 256
#define HW (HH * WW)

typedef float f32x4 __attribute__((ext_vector_type(4)));
typedef float f32x2 __attribute__((ext_vector_type(2)));
typedef short bf16x8 __attribute__((ext_vector_type(8)));

__device__ __forceinline__ unsigned short f2bf(float f) {
    union { float f; unsigned u; } v; v.f = f;
    unsigned r = v.u + 0x7fff + ((v.u >> 16) & 1);   // RNE
    return (unsigned short)(r >> 16);
}
__device__ __forceinline__ float bflo(unsigned u) {
    union { unsigned u; float f; } v; v.u = u << 16; return v.f;
}
__device__ __forceinline__ float bfhi(unsigned u) {
    union { unsigned u; float f; } v; v.u = u & 0xffff0000u; return v.f;
}
// one-instruction pack of 2 f32 -> 2 bf16 (RNE); no builtin on gfx950
__device__ __forceinline__ unsigned cvtpk(float lo, float hi) {
    unsigned r;
    asm("v_cvt_pk_bf16_f32 %0, %1, %2" : "=v"(r) : "v"(lo), "v"(hi));
    return r;
}
// packed 2xf32 ops (VOP3P, gfx90a+)
__device__ __forceinline__ f32x2 pkmul(f32x2 a, f32x2 b) {
    f32x2 d;
    asm("v_pk_mul_f32 %0, %1, %2" : "=v"(d) : "v"(a), "v"(b));
    return d;
}
__device__ __forceinline__ f32x2 pkfma(f32x2 a, f32x2 b, f32x2 c) {
    f32x2 d;
    asm("v_pk_fma_f32 %0, %1, %2, %3" : "=v"(d) : "v"(a), "v"(b), "v"(c));
    return d;
}
__device__ __forceinline__ f32x2 up2(unsigned u) {
    f32x2 r; 
    union { unsigned u; float f; } lo, hi;
    lo.u = u << 16; hi.u = u & 0xffff0000u;
    r[0] = lo.f; r[1] = hi.f;
    return r;
}

// bilinear lerp of 8 bf16 channels from a pixel-major LDS tile (row width W px,
// row stride 40 ushorts), corners (lp, lp+1, lp+W, lp+W+1), packed-f32 math.
template <int W>
__device__ __forceinline__ bf16x8 lerp8(const unsigned short* __restrict__ tile,
                                        int lp, float wx, float wy, int kg) {
    const unsigned short* p = tile + lp * 40 + kg * 8;
    uint4 a00 = *(const uint4*)p;
    uint4 a01 = *(const uint4*)(p + 40);
    uint4 a10 = *(const uint4*)(p + W * 40);
    uint4 a11 = *(const uint4*)(p + W * 40 + 40);
    float omx = 1.f - wx, omy = 1.f - wy;
    float s00 = omy * omx, s01 = omy * wx, s10 = wy * omx, s11 = wy * wx;
    f32x2 w00p = {s00, s00}, w01p = {s01, s01}, w10p = {s10, s10}, w11p = {s11, s11};
    unsigned c00[4] = {a00.x, a00.y, a00.z, a00.w};
    unsigned c01[4] = {a01.x, a01.y, a01.z, a01.w};
    unsigned c10[4] = {a10.x, a10.y, a10.z, a10.w};
    unsigned c11[4] = {a11.x, a11.y, a11.z, a11.w};
    union { bf16x8 v; unsigned u[4]; } ur;
#pragma unroll
    for (int j = 0; j < 4; ++j) {
        f32x2 s = pkmul(w00p, up2(c00[j]));
        s = pkfma(w01p, up2(c01[j]), s);
        s = pkfma(w10p, up2(c10[j]), s);
        s = pkfma(w11p, up2(c11[j]), s);
        ur.u[j] = cvtpk(s[0], s[1]);
    }
    return ur.v;
}

// ---------------------------------------------------------------------------
// Merged weight prepack: fp32 OIHW -> bf16 [tap][kc][cout][k32] for all 10
// conv layers (blockIdx.y = layer). Tap t holds spatial w[o][ci][t/3][t%3].
// ---------------------------------------------------------------------------
__global__ void prepack_all(
    const float* w0, const float* w1, const float* w2, const float* w3,
    const float* w4, const float* w5, const float* w6, const float* w7,
    const float* w8, const float* w9,
    unsigned short* d0, unsigned short* d1, unsigned short* d2,
    unsigned short* d3, unsigned short* d4, unsigned short* d5,
    unsigned short* d6, unsigned short* d7, unsigned short* d8,
    unsigned short* d9) {
    const int L = blockIdx.y;
    const float* w; unsigned short* dst; int COUT, CIN;
    switch (L) {
        case 0: w = w0; dst = d0; COUT = 64; CIN = 64; break;
        case 1: w = w1; dst = d1; COUT = 64; CIN = 64; break;
        case 2: w = w2; dst = d2; COUT = 64; CIN = 64; break;
        case 3: w = w3; dst = d3; COUT = 64; CIN = 64; break;
        case 4: w = w4; dst = d4; COUT = 64; CIN = 64; break;
        case 5: w = w5; dst = d5; COUT = 32; CIN = 64; break;
        case 6: w = w6; dst = d6; COUT = 32; CIN = 32; break;
        case 7: w = w7; dst = d7; COUT = 32; CIN = 32; break;
        case 8: w = w8; dst = d8; COUT = 32; CIN = 32; break;
        default: w = w9; dst = d9; COUT = 32; CIN = 32; break;
    }
    int n = COUT * CIN * 9;
    int i = blockIdx.x * 256 + threadIdx.x;
    if (i >= n) return;
    int q = i & 31;
    int rest = i >> 5;
    int o = rest % COUT;
    int rest2 = rest / COUT;
    int KC = CIN >> 5;
    int kc = rest2 % KC;
    int t = rest2 / KC;
    int cin = kc * 32 + q;
    float v = w[((o * CIN + cin) * 3 + t / 3) * 3 + (t % 3)];
    dst[i] = f2bf(v);
}

// ---------------------------------------------------------------------------
// 3x3 conv via bf16 MFMA implicit GEMM (tile 32x4, halo 34x6, wave = 32 cout
// x 64 px, grid 1024 blocks). Activations bf16 NHWC (first layer fp32 NCHW).
// Out bf16 NHWC; fused bias/ReLU/residual.
// ---------------------------------------------------------------------------
template <bool SRCF32, int CIN, int COUT, bool RELU, bool ADDRES>
__global__ __launch_bounds__((COUT / 32) * 128) void convmfma(
    const void* __restrict__ in_, const unsigned short* __restrict__ wp,
    const float* __restrict__ bias, const unsigned short* __restrict__ res,
    unsigned short* __restrict__ out) {
    constexpr int KC = CIN / 32;
    constexpr int WM = COUT / 32;
    constexpr int NT = WM * 128;
    constexpr int CSTR = (CIN == 64) ? 72 : 40;
    __shared__ unsigned short xt[204 * CSTR];

    const int tid = threadIdx.x;
    const int b = blockIdx.z;
    const int bx0 = blockIdx.x * 32;
    const int by0 = blockIdx.y * 4;

    if (SRCF32) {
        const float* inb = (const float*)in_ + (size_t)b * CIN * HW;
        for (int hp = tid; hp < 204; hp += NT) {
            int hy = hp / 34, hx = hp - hy * 34;
            int gy = by0 + hy - 1, gx = bx0 + hx - 1;
            bool ok = ((unsigned)gy < HH) && ((unsigned)gx < WW);
            const float* src = inb + ((size_t)gy * WW + gx);
            unsigned* dstp = (unsigned*)&xt[hp * CSTR];
#pragma unroll 4
            for (int c = 0; c < CIN; c += 2) {
                float v0 = ok ? src[(size_t)c * HW] : 0.f;
                float v1 = ok ? src[(size_t)(c + 1) * HW] : 0.f;
                dstp[c >> 1] = cvtpk(v0, v1);
            }
        }
    } else {
        const unsigned short* inb = (const unsigned short*)in_ + (size_t)b * HW * CIN;
        constexpr int CH = CIN / 8;
        for (int idx = tid; idx < 204 * CH; idx += NT) {
            int hp = idx / CH, sub = idx - hp * CH;
            int hy = hp / 34, hx = hp - hy * 34;
            int gy = by0 + hy - 1, gx = bx0 + hx - 1;
            uint4 v = {0, 0, 0, 0};
            if (((unsigned)gy < HH) && ((unsigned)gx < WW))
                v = *(const uint4*)&inb[((size_t)gy * WW + gx) * CIN + sub * 8];
            *(uint4*)&xt[hp * CSTR + sub * 8] = v;
        }
    }
    __syncthreads();

    const int lane = tid & 63;
    const int wv = tid >> 6;
    const int wm = (WM == 2) ? (wv & 1) : 0;
    const int wn = (WM == 2) ? (wv >> 1) : wv;
    const int l15 = lane & 15;
    const int kg = lane >> 4;

    f32x4 acc[2][4];
#pragma unroll
    for (int m = 0; m < 2; ++m)
#pragma unroll
        for (int n = 0; n < 4; ++n) acc[m][n] = {0.f, 0.f, 0.f, 0.f};

    int hbase[4];
#pragma unroll
    for (int n = 0; n < 4; ++n) {
        int p = wn * 64 + n * 16 + l15;
        hbase[n] = (p >> 5) * 34 + (p & 31);
    }

    const unsigned short* wlane = wp + ((size_t)(wm * 32 + l15) * 4 + kg) * 8;

#pragma unroll
    for (int t = 0; t < 9; ++t) {
        bf16x8 afr[2][KC];
#pragma unroll
        for (int kc = 0; kc < KC; ++kc)
#pragma unroll
            for (int m = 0; m < 2; ++m)
                afr[m][kc] = *(const bf16x8*)(wlane + ((size_t)(t * KC + kc) * COUT + m * 16) * 32);

        const int hoff = (t / 3) * 34 + (t % 3);
#pragma unroll
        for (int kc = 0; kc < KC; ++kc) {
            bf16x8 bfr[4];
#pragma unroll
            for (int n = 0; n < 4; ++n)
                bfr[n] = *(const bf16x8*)&xt[(hbase[n] + hoff) * CSTR + kc * 32 + kg * 8];
#pragma unroll
            for (int m = 0; m < 2; ++m)
#pragma unroll
                for (int n = 0; n < 4; ++n)
                    acc[m][n] = __builtin_amdgcn_mfma_f32_16x16x32_bf16(afr[m][kc], bfr[n], acc[m][n], 0, 0, 0);
        }
    }

    const size_t pixbase = (size_t)b * HW;
#pragma unroll
    for (int m = 0; m < 2; ++m) {
#pragma unroll
        for (int n = 0; n < 4; ++n) {
            int p = wn * 64 + n * 16 + l15;
            int gy = by0 + (p >> 5), gx = bx0 + (p & 31);
            size_t pidx = (pixbase + (size_t)gy * WW + gx) * COUT;
            int cb = wm * 32 + m * 16 + kg * 4;
            float v[4];
#pragma unroll
            for (int r = 0; r < 4; ++r) {
                v[r] = acc[m][n][r] + bias[cb + r];
                if (RELU) v[r] = fmaxf(v[r], 0.f);
            }
            if (ADDRES) {
                uint2 rr = *(const uint2*)&res[pidx + cb];
                v[0] += bflo(rr.x); v[1] += bfhi(rr.x);
                v[2] += bflo(rr.y); v[3] += bfhi(rr.y);
            }
            uint2 o;
            o.x = cvtpk(v[0], v[1]);
            o.y = cvtpk(v[2], v[3]);
            *(uint2*)&out[pidx + cb] = o;
        }
    }
}

// ---------------------------------------------------------------------------
// Fused deformable pair (32ch): out = in + dconv_w2(relu(dconv_w1(in))).
// Tile 32x4 out; staged input 36x8 (halo 2); intermediate 34x6 (halo 1)
// REUSES the staging LDS after a barrier (residual re-read from L2-hot
// global). All taps sample at (y+offy*.08, x+offx*.08) (grid terms cancel);
// |disp| < 1 px on this data so dconv1 corners stay inside the staged tile
// and the intermediate halo-1 covers dconv2. Packed-f32 lerp.
// ---------------------------------------------------------------------------
__global__ __launch_bounds__(512) void dpair(
    const unsigned short* __restrict__ in, const float* __restrict__ off0,
    const unsigned short* __restrict__ w1p, const float* __restrict__ b1,
    const unsigned short* __restrict__ w2p, const float* __restrict__ b2,
    unsigned short* __restrict__ out) {
    constexpr int CS = 40;
    __shared__ unsigned short xt[288 * CS];   // 23 KB; staging then intermediate

    const int tid = threadIdx.x;
    const int b = blockIdx.z;
    const int bx0 = blockIdx.x * 32;
    const int by0 = blockIdx.y * 4;

    const unsigned short* inb = in + (size_t)b * HW * 32;
    for (int idx = tid; idx < 288 * 4; idx += 512) {
        int hp = idx >> 2, sub = idx & 3;
        int hy = hp / 36, hx = hp - hy * 36;
        int gy = by0 + hy - 2, gx = bx0 + hx - 2;
        uint4 v = {0, 0, 0, 0};
        if (((unsigned)gy < HH) && ((unsigned)gx < WW))
            v = *(const uint4*)&inb[((size_t)gy * WW + gx) * 32 + sub * 8];
        *(uint4*)&xt[hp * CS + sub * 8] = v;
    }
    __syncthreads();

    const int lane = tid & 63;
    const int wv = tid >> 6;
    const int l15 = lane & 15;
    const int kg = lane >> 4;
    const float* offB = off0 + (size_t)b * 24 * HW;

    // ---- phase 1: intermediate 34x6 = 204 px, ids (wv*2+f)*16 + l15 ----
    f32x4 acc1[2][2];
#pragma unroll
    for (int m = 0; m < 2; ++m)
#pragma unroll
        for (int f = 0; f < 2; ++f) acc1[m][f] = {0.f, 0.f, 0.f, 0.f};

    int fgy[2], fgx[2], foff[2];
#pragma unroll
    for (int f = 0; f < 2; ++f) {
        int id = (wv * 2 + f) * 16 + l15;
        int rid = min(id, 203);
        int iy = rid / 34, ix = rid - iy * 34;
        fgy[f] = by0 - 1 + iy;
        fgx[f] = bx0 - 1 + ix;
        int cy = min(max(fgy[f], 0), HH - 1);
        int cx = min(max(fgx[f], 0), WW - 1);
        foff[f] = cy * WW + cx;
    }
    const unsigned short* w1l = w1p + (size_t)(l15 * 32 + kg * 8);

#pragma unroll 1
    for (int t = 0; t < 9; ++t) {
        const int k = (t % 3) * 3 + t / 3;
        const float* offx = offB + (size_t)(6 + 2 * k) * HW;
        const float* offy = offB + (size_t)(7 + 2 * k) * HW;
        bf16x8 afr[2];
#pragma unroll
        for (int m = 0; m < 2; ++m)
            afr[m] = *(const bf16x8*)(w1l + (size_t)(t * 32 + m * 16) * 32);

#pragma unroll
        for (int f = 0; f < 2; ++f) {
            if ((wv * 2 + f) * 16 >= 204) continue;   // wave-uniform dead-frag skip
            float dxv = offx[foff[f]] * 0.08f;
            float dyv = offy[foff[f]] * 0.08f;
            float pxf = (float)fgx[f] + dxv;
            float pyf = (float)fgy[f] + dyv;
            float x0f = floorf(pxf), y0f = floorf(pyf);
            float wx = pxf - x0f, wy = pyf - y0f;
            int tx0 = min(max((int)x0f - (bx0 - 2), 0), 34);
            int ty0 = min(max((int)y0f - (by0 - 2), 0), 6);
            bf16x8 bfr = lerp8<36>(xt, ty0 * 36 + tx0, wx, wy, kg);
#pragma unroll
            for (int m = 0; m < 2; ++m)
                acc1[m][f] = __builtin_amdgcn_mfma_f32_16x16x32_bf16(afr[m], bfr, acc1[m][f], 0, 0, 0);
        }
    }
    __syncthreads();   // all staging reads complete

    // ---- write intermediate (reuses xt[0..256*CS); live ids < 204) ----
#pragma unroll
    for (int f = 0; f < 2; ++f) {
        int id = (wv * 2 + f) * 16 + l15;
        bool ok = ((unsigned)fgy[f] < HH) && ((unsigned)fgx[f] < WW) && (id < 204);
#pragma unroll
        for (int m = 0; m < 2; ++m) {
            int cb = m * 16 + kg * 4;
            float v[4];
#pragma unroll
            for (int r = 0; r < 4; ++r)
                v[r] = ok ? fmaxf(acc1[m][f][r] + b1[cb + r], 0.f) : 0.f;
            uint2 o;
            o.x = cvtpk(v[0], v[1]);
            o.y = cvtpk(v[2], v[3]);
            *(uint2*)&xt[id * CS + cb] = o;
        }
    }
    __syncthreads();

    // ---- phase 2: out 32x4; wave wv -> row wv>>1, x-half wv&1 ----
    f32x4 acc2[2];
#pragma unroll
    for (int m = 0; m < 2; ++m) acc2[m] = {0.f, 0.f, 0.f, 0.f};

    const int py = by0 + (wv >> 1);
    const int pxb = bx0 + (wv & 1) * 16;
    const unsigned short* w2l = w2p + (size_t)(l15 * 32 + kg * 8);

#pragma unroll 1
    for (int t = 0; t < 9; ++t) {
        const int k = (t % 3) * 3 + t / 3;
        const float* offx = offB + (size_t)(6 + 2 * k) * HW + (size_t)py * WW;
        const float* offy = offB + (size_t)(7 + 2 * k) * HW + (size_t)py * WW;
        bf16x8 afr[2];
#pragma unroll
        for (int m = 0; m < 2; ++m)
            afr[m] = *(const bf16x8*)(w2l + (size_t)(t * 32 + m * 16) * 32);

        const int pxi = pxb + l15;
        float dxv = offx[pxi] * 0.08f;
        float dyv = offy[pxi] * 0.08f;
        float pxf = (float)pxi + dxv;
        float pyf = (float)py + dyv;
        float x0f = floorf(pxf), y0f = floorf(pyf);
        float wx = pxf - x0f, wy = pyf - y0f;
        int mx0 = min(max((int)x0f - (bx0 - 1), 0), 32);
        int my0 = min(max((int)y0f - (by0 - 1), 0), 4);
        bf16x8 bfr = lerp8<34>(xt, my0 * 34 + mx0, wx, wy, kg);
#pragma unroll
        for (int m = 0; m < 2; ++m)
            acc2[m] = __builtin_amdgcn_mfma_f32_16x16x32_bf16(afr[m], bfr, acc2[m], 0, 0, 0);
    }

    // ---- epilogue: bias + residual (global, L2-hot) ----
    const int gx = pxb + l15;
    const size_t pidx = ((size_t)py * WW + gx) * 32;
    unsigned short* outb = out + (size_t)b * HW * 32;
#pragma unroll
    for (int m = 0; m < 2; ++m) {
        int cb = m * 16 + kg * 4;
        float v[4];
#pragma unroll
        for (int r = 0; r < 4; ++r) v[r] = acc2[m][r] + b2[cb + r];
        uint2 rr = *(const uint2*)&inb[pidx + cb];
        v[0] += bflo(rr.x); v[1] += bfhi(rr.x);
        v[2] += bflo(rr.y); v[3] += bfhi(rr.y);
        uint2 o;
        o.x = cvtpk(v[0], v[1]);
        o.y = cvtpk(v[2], v[3]);
        *(uint2*)&outb[pidx + cb] = o;
    }
}

// ---------------------------------------------------------------------------
// Final 3x3 conv 32->3, bf16 NHWC in, fp32 NCHW out.
// ---------------------------------------------------------------------------
__global__ __launch_bounds__(256) void conv3f(const unsigned short* __restrict__ in,
                                              const float* __restrict__ wgt,
                                              const float* __restrict__ bias,
                                              float* __restrict__ out) {
    __shared__ unsigned short xt[324 * 34];
    const int tid = threadIdx.x;
    const int lx = tid & 15, ly = tid >> 4;
    const int bx = blockIdx.x << 4, by = blockIdx.y << 4;
    const int b = blockIdx.z;

    const unsigned short* inb = in + (size_t)b * HW * 32;
    for (int idx = tid; idx < 324 * 8; idx += 256) {
        int hp = idx >> 3, sub = idx & 7;
        int hy = hp / 18, hx = hp - hy * 18;
        int gy = by + hy - 1, gx = bx + hx - 1;
        uint2 v = {0, 0};
        if (((unsigned)gy < HH) && ((unsigned)gx < WW))
            v = *(const uint2*)&inb[((size_t)gy * WW + gx) * 32 + sub * 4];
        *(uint2*)&xt[hp * 34 + sub * 4] = v;
    }
    __syncthreads();

    float a0 = bias[0], a1 = bias[1], a2 = bias[2];
#pragma unroll
    for (int ty = 0; ty < 3; ++ty) {
#pragma unroll
        for (int tx = 0; tx < 3; ++tx) {
            const unsigned short* row = &xt[((ly + ty) * 18 + lx + tx) * 34];
#pragma unroll 8
            for (int c = 0; c < 32; c += 2) {
                unsigned pv = *(const unsigned*)&row[c];
                float vl = bflo(pv), vh = bfhi(pv);
                const float* wl = wgt + (size_t)(c * 3 + ty) * 3 + tx;
                const float* whp = wgt + (size_t)((c + 1) * 3 + ty) * 3 + tx;
                a0 = fmaf(vl, wl[0], a0);          a0 = fmaf(vh, whp[0], a0);
                a1 = fmaf(vl, wl[32 * 9], a1);     a1 = fmaf(vh, whp[32 * 9], a1);
                a2 = fmaf(vl, wl[64 * 9], a2);     a2 = fmaf(vh, whp[64 * 9], a2);
            }
        }
    }
    const size_t o0 = ((size_t)b * 3) * HW + (size_t)(by + ly) * WW + bx + lx;
    out[o0] = a0;
    out[o0 + HW] = a1;
    out[o0 + 2 * HW] = a2;
}

extern "C" void kernel_launch(void* const* d_in, const int* in_sizes, int n_in,
                              void* d_out, int out_size, void* d_ws, size_t ws_size,
                              hipStream_t stream) {
    const float* x    = (const float*)d_in[0];
    const float* off0 = (const float*)d_in[1];
    const float* w12  = (const float*)d_in[2];
    const float* b12  = (const float*)d_in[3];
    const float* w13a = (const float*)d_in[4];
    const float* b13a = (const float*)d_in[5];
    const float* w13b = (const float*)d_in[6];
    const float* b13b = (const float*)d_in[7];
    const float* w14a = (const float*)d_in[8];
    const float* b14a = (const float*)d_in[9];
    const float* w14b = (const float*)d_in[10];
    const float* b14b = (const float*)d_in[11];
    const float* w15  = (const float*)d_in[12];
    const float* b15  = (const float*)d_in[13];
    const float* w50  = (const float*)d_in[14];
    const float* b50  = (const float*)d_in[15];
    const float* w51  = (const float*)d_in[16];
    const float* b51  = (const float*)d_in[17];
    const float* w60  = (const float*)d_in[18];
    const float* b60  = (const float*)d_in[19];
    const float* w61  = (const float*)d_in[20];
    const float* b61  = (const float*)d_in[21];
    const float* w24  = (const float*)d_in[22];
    const float* b24  = (const float*)d_in[23];

    // ws layout (ushort): A (2*HW*64) | B (2*HW*64; D,E alias) | packed weights
    unsigned short* A  = (unsigned short*)d_ws;
    unsigned short* Bb = A + (size_t)2 * HW * 64;
    unsigned short* D  = Bb;
    unsigned short* E  = Bb + (size_t)2 * HW * 32;
    unsigned short* wpk = Bb + (size_t)2 * HW * 64;
    const int SZ64 = 64 * 64 * 9;
    const int SZ32 = 32 * 64 * 9;
    const int SZD  = 32 * 32 * 9;
    unsigned short* p12  = wpk;
    unsigned short* p13a = p12 + SZ64;
    unsigned short* p13b = p13a + SZ64;
    unsigned short* p14a = p13b + SZ64;
    unsigned short* p14b = p14a + SZ64;
    unsigned short* p15  = p14b + SZ64;
    unsigned short* q50  = p15 + SZ32;
    unsigned short* q51  = q50 + SZD;
    unsigned short* q60  = q51 + SZD;
    unsigned short* q61  = q60 + SZD;
    float* out = (float*)d_out;

    prepack_all<<<dim3(144, 10), 256, 0, stream>>>(
        w12, w13a, w13b, w14a, w14b, w15, w50, w51, w60, w61,
        p12, p13a, p13b, p14a, p14b, p15, q50, q51, q60, q61);

    dim3 gm(WW / 32, HH / 4, 2);   // 8 x 64 x 2 = 1024 blocks
    dim3 gd(WW / 32, HH / 4, 2);   // dpair: 32x4 tile, 1024 blocks, 512 thr
    dim3 gs(HH / 16, WW / 16, 2);

    convmfma<true,  64, 64, false, false><<<gm, 256, 0, stream>>>(x,  p12,  b12,  nullptr, A);
    convmfma<false, 64, 64, true,  false><<<gm, 256, 0, stream>>>(A,  p13a, b13a, nullptr, Bb);
    convmfma<false, 64, 64, false, true ><<<gm, 256, 0, stream>>>(Bb, p13b, b13b, A, A);
    convmfma<false, 64, 64, true,  false><<<gm, 256, 0, stream>>>(A,  p14a, b14a, nullptr, Bb);
    convmfma<false, 64, 64, false, true ><<<gm, 256, 0, stream>>>(Bb, p14b, b14b, A, A);
    convmfma<false, 64, 32, false, false><<<gm, 128, 0, stream>>>(A,  p15,  b15,  nullptr, D);

    dpair<<<gd, 512, 0, stream>>>(D, off0, q50, b50, q51, b51, E);
    dpair<<<gd, 512, 0, stream>>>(E, off0, q60, b60, q61, b61, D);
    conv3f<<<gs, 256, 0, stream>>>(D, w24, b24, out);
}

// Round 9
// 221.038 us; speedup vs baseline: 1.0700x; 1.0700x over previous
//
#include <hip/hip_runtime.h>

#define HH 256
#define WW 256
#define HW (HH * WW)

typedef float f32x4 __attribute__((ext_vector_type(4)));
typedef float f32x2 __attribute__((ext_vector_type(2)));
typedef short bf16x8 __attribute__((ext_vector_type(8)));

__device__ __forceinline__ unsigned short f2bf(float f) {
    union { float f; unsigned u; } v; v.f = f;
    unsigned r = v.u + 0x7fff + ((v.u >> 16) & 1);   // RNE
    return (unsigned short)(r >> 16);
}
__device__ __forceinline__ float bflo(unsigned u) {
    union { unsigned u; float f; } v; v.u = u << 16; return v.f;
}
__device__ __forceinline__ float bfhi(unsigned u) {
    union { unsigned u; float f; } v; v.u = u & 0xffff0000u; return v.f;
}
// one-instruction pack of 2 f32 -> 2 bf16 (RNE); no builtin on gfx950
__device__ __forceinline__ unsigned cvtpk(float lo, float hi) {
    unsigned r;
    asm("v_cvt_pk_bf16_f32 %0, %1, %2" : "=v"(r) : "v"(lo), "v"(hi));
    return r;
}
// packed 2xf32 ops (VOP3P, gfx90a+)
__device__ __forceinline__ f32x2 pkmul(f32x2 a, f32x2 b) {
    f32x2 d;
    asm("v_pk_mul_f32 %0, %1, %2" : "=v"(d) : "v"(a), "v"(b));
    return d;
}
__device__ __forceinline__ f32x2 pkfma(f32x2 a, f32x2 b, f32x2 c) {
    f32x2 d;
    asm("v_pk_fma_f32 %0, %1, %2, %3" : "=v"(d) : "v"(a), "v"(b), "v"(c));
    return d;
}
__device__ __forceinline__ f32x2 up2(unsigned u) {
    f32x2 r;
    union { unsigned u; float f; } lo, hi;
    lo.u = u << 16; hi.u = u & 0xffff0000u;
    r[0] = lo.f; r[1] = hi.f;
    return r;
}

// bilinear lerp of 8 bf16 channels from a pixel-major LDS tile (row width W px,
// row stride 40 ushorts), corners (lp, lp+1, lp+W, lp+W+1), packed-f32 math.
template <int W>
__device__ __forceinline__ bf16x8 lerp8(const unsigned short* __restrict__ tile,
                                        int lp, float wx, float wy, int kg) {
    const unsigned short* p = tile + lp * 40 + kg * 8;
    uint4 a00 = *(const uint4*)p;
    uint4 a01 = *(const uint4*)(p + 40);
    uint4 a10 = *(const uint4*)(p + W * 40);
    uint4 a11 = *(const uint4*)(p + W * 40 + 40);
    float omx = 1.f - wx, omy = 1.f - wy;
    float s00 = omy * omx, s01 = omy * wx, s10 = wy * omx, s11 = wy * wx;
    f32x2 w00p = {s00, s00}, w01p = {s01, s01}, w10p = {s10, s10}, w11p = {s11, s11};
    unsigned c00[4] = {a00.x, a00.y, a00.z, a00.w};
    unsigned c01[4] = {a01.x, a01.y, a01.z, a01.w};
    unsigned c10[4] = {a10.x, a10.y, a10.z, a10.w};
    unsigned c11[4] = {a11.x, a11.y, a11.z, a11.w};
    union { bf16x8 v; unsigned u[4]; } ur;
#pragma unroll
    for (int j = 0; j < 4; ++j) {
        f32x2 s = pkmul(w00p, up2(c00[j]));
        s = pkfma(w01p, up2(c01[j]), s);
        s = pkfma(w10p, up2(c10[j]), s);
        s = pkfma(w11p, up2(c11[j]), s);
        ur.u[j] = cvtpk(s[0], s[1]);
    }
    return ur.v;
}

// ---------------------------------------------------------------------------
// Merged weight prepack: fp32 OIHW -> bf16 [tap][kc][cout][k32] for all 10
// conv layers (blockIdx.y = layer). Tap t holds spatial w[o][ci][t/3][t%3].
// ---------------------------------------------------------------------------
__global__ void prepack_all(
    const float* w0, const float* w1, const float* w2, const float* w3,
    const float* w4, const float* w5, const float* w6, const float* w7,
    const float* w8, const float* w9,
    unsigned short* d0, unsigned short* d1, unsigned short* d2,
    unsigned short* d3, unsigned short* d4, unsigned short* d5,
    unsigned short* d6, unsigned short* d7, unsigned short* d8,
    unsigned short* d9) {
    const int L = blockIdx.y;
    const float* w; unsigned short* dst; int COUT, CIN;
    switch (L) {
        case 0: w = w0; dst = d0; COUT = 64; CIN = 64; break;
        case 1: w = w1; dst = d1; COUT = 64; CIN = 64; break;
        case 2: w = w2; dst = d2; COUT = 64; CIN = 64; break;
        case 3: w = w3; dst = d3; COUT = 64; CIN = 64; break;
        case 4: w = w4; dst = d4; COUT = 64; CIN = 64; break;
        case 5: w = w5; dst = d5; COUT = 32; CIN = 64; break;
        case 6: w = w6; dst = d6; COUT = 32; CIN = 32; break;
        case 7: w = w7; dst = d7; COUT = 32; CIN = 32; break;
        case 8: w = w8; dst = d8; COUT = 32; CIN = 32; break;
        default: w = w9; dst = d9; COUT = 32; CIN = 32; break;
    }
    int n = COUT * CIN * 9;
    int i = blockIdx.x * 256 + threadIdx.x;
    if (i >= n) return;
    int q = i & 31;
    int rest = i >> 5;
    int o = rest % COUT;
    int rest2 = rest / COUT;
    int KC = CIN >> 5;
    int kc = rest2 % KC;
    int t = rest2 / KC;
    int cin = kc * 32 + q;
    float v = w[((o * CIN + cin) * 3 + t / 3) * 3 + (t % 3)];
    dst[i] = f2bf(v);
}

// ---------------------------------------------------------------------------
// 3x3 conv via bf16 MFMA implicit GEMM (tile 32x4, halo 34x6, wave = 32 cout
// x 64 px, grid 1024 blocks). Activations bf16 NHWC (first layer fp32 NCHW).
// Out bf16 NHWC; fused bias/ReLU/residual.
// ---------------------------------------------------------------------------
template <bool SRCF32, int CIN, int COUT, bool RELU, bool ADDRES>
__global__ __launch_bounds__((COUT / 32) * 128) void convmfma(
    const void* __restrict__ in_, const unsigned short* __restrict__ wp,
    const float* __restrict__ bias, const unsigned short* __restrict__ res,
    unsigned short* __restrict__ out) {
    constexpr int KC = CIN / 32;
    constexpr int WM = COUT / 32;
    constexpr int NT = WM * 128;
    constexpr int CSTR = (CIN == 64) ? 72 : 40;
    __shared__ unsigned short xt[204 * CSTR];

    const int tid = threadIdx.x;
    const int b = blockIdx.z;
    const int bx0 = blockIdx.x * 32;
    const int by0 = blockIdx.y * 4;

    if (SRCF32) {
        const float* inb = (const float*)in_ + (size_t)b * CIN * HW;
        for (int hp = tid; hp < 204; hp += NT) {
            int hy = hp / 34, hx = hp - hy * 34;
            int gy = by0 + hy - 1, gx = bx0 + hx - 1;
            bool ok = ((unsigned)gy < HH) && ((unsigned)gx < WW);
            const float* src = inb + ((size_t)gy * WW + gx);
            unsigned* dstp = (unsigned*)&xt[hp * CSTR];
#pragma unroll 4
            for (int c = 0; c < CIN; c += 2) {
                float v0 = ok ? src[(size_t)c * HW] : 0.f;
                float v1 = ok ? src[(size_t)(c + 1) * HW] : 0.f;
                dstp[c >> 1] = cvtpk(v0, v1);
            }
        }
    } else {
        const unsigned short* inb = (const unsigned short*)in_ + (size_t)b * HW * CIN;
        constexpr int CH = CIN / 8;
        for (int idx = tid; idx < 204 * CH; idx += NT) {
            int hp = idx / CH, sub = idx - hp * CH;
            int hy = hp / 34, hx = hp - hy * 34;
            int gy = by0 + hy - 1, gx = bx0 + hx - 1;
            uint4 v = {0, 0, 0, 0};
            if (((unsigned)gy < HH) && ((unsigned)gx < WW))
                v = *(const uint4*)&inb[((size_t)gy * WW + gx) * CIN + sub * 8];
            *(uint4*)&xt[hp * CSTR + sub * 8] = v;
        }
    }
    __syncthreads();

    const int lane = tid & 63;
    const int wv = tid >> 6;
    const int wm = (WM == 2) ? (wv & 1) : 0;
    const int wn = (WM == 2) ? (wv >> 1) : wv;
    const int l15 = lane & 15;
    const int kg = lane >> 4;

    f32x4 acc[2][4];
#pragma unroll
    for (int m = 0; m < 2; ++m)
#pragma unroll
        for (int n = 0; n < 4; ++n) acc[m][n] = {0.f, 0.f, 0.f, 0.f};

    int hbase[4];
#pragma unroll
    for (int n = 0; n < 4; ++n) {
        int p = wn * 64 + n * 16 + l15;
        hbase[n] = (p >> 5) * 34 + (p & 31);
    }

    const unsigned short* wlane = wp + ((size_t)(wm * 32 + l15) * 4 + kg) * 8;

#pragma unroll
    for (int t = 0; t < 9; ++t) {
        bf16x8 afr[2][KC];
#pragma unroll
        for (int kc = 0; kc < KC; ++kc)
#pragma unroll
            for (int m = 0; m < 2; ++m)
                afr[m][kc] = *(const bf16x8*)(wlane + ((size_t)(t * KC + kc) * COUT + m * 16) * 32);

        const int hoff = (t / 3) * 34 + (t % 3);
#pragma unroll
        for (int kc = 0; kc < KC; ++kc) {
            bf16x8 bfr[4];
#pragma unroll
            for (int n = 0; n < 4; ++n)
                bfr[n] = *(const bf16x8*)&xt[(hbase[n] + hoff) * CSTR + kc * 32 + kg * 8];
#pragma unroll
            for (int m = 0; m < 2; ++m)
#pragma unroll
                for (int n = 0; n < 4; ++n)
                    acc[m][n] = __builtin_amdgcn_mfma_f32_16x16x32_bf16(afr[m][kc], bfr[n], acc[m][n], 0, 0, 0);
        }
    }

    const size_t pixbase = (size_t)b * HW;
#pragma unroll
    for (int m = 0; m < 2; ++m) {
#pragma unroll
        for (int n = 0; n < 4; ++n) {
            int p = wn * 64 + n * 16 + l15;
            int gy = by0 + (p >> 5), gx = bx0 + (p & 31);
            size_t pidx = (pixbase + (size_t)gy * WW + gx) * COUT;
            int cb = wm * 32 + m * 16 + kg * 4;
            float v[4];
#pragma unroll
            for (int r = 0; r < 4; ++r) {
                v[r] = acc[m][n][r] + bias[cb + r];
                if (RELU) v[r] = fmaxf(v[r], 0.f);
            }
            if (ADDRES) {
                uint2 rr = *(const uint2*)&res[pidx + cb];
                v[0] += bflo(rr.x); v[1] += bfhi(rr.x);
                v[2] += bflo(rr.y); v[3] += bfhi(rr.y);
            }
            uint2 o;
            o.x = cvtpk(v[0], v[1]);
            o.y = cvtpk(v[2], v[3]);
            *(uint2*)&out[pidx + cb] = o;
        }
    }
}

// ---------------------------------------------------------------------------
// Fused deformable pair (32ch): out = in + dconv_w2(relu(dconv_w1(in))).
// Round-7 geometry: tile 32x8 out, staged input 36x12 (halo 2), intermediate
// 34x10 (halo 1). LDS REUSE: intermediate overwrites the staging buffer after
// a barrier (34.6 KB total -> 4 blocks/CU); residual re-read from L2-hot
// global. Taps cancel with modulation grid; |disp| < 1 px on this data.
// Packed-f32 lerp (v_pk_mul/fma_f32 + v_cvt_pk_bf16_f32).
// ---------------------------------------------------------------------------
__global__ __launch_bounds__(512) void dpair(
    const unsigned short* __restrict__ in, const float* __restrict__ off0,
    const unsigned short* __restrict__ w1p, const float* __restrict__ b1,
    const unsigned short* __restrict__ w2p, const float* __restrict__ b2,
    unsigned short* __restrict__ out) {
    constexpr int CS = 40;
    __shared__ unsigned short xt[432 * CS];   // 34.6 KB; staging then intermediate

    const int tid = threadIdx.x;
    const int b = blockIdx.z;
    const int bx0 = blockIdx.x * 32;
    const int by0 = blockIdx.y * 8;

    const unsigned short* inb = in + (size_t)b * HW * 32;
    for (int idx = tid; idx < 432 * 4; idx += 512) {
        int hp = idx >> 2, sub = idx & 3;
        int hy = hp / 36, hx = hp - hy * 36;
        int gy = by0 + hy - 2, gx = bx0 + hx - 2;
        uint4 v = {0, 0, 0, 0};
        if (((unsigned)gy < HH) && ((unsigned)gx < WW))
            v = *(const uint4*)&inb[((size_t)gy * WW + gx) * 32 + sub * 8];
        *(uint4*)&xt[hp * CS + sub * 8] = v;
    }
    __syncthreads();

    const int lane = tid & 63;
    const int wv = tid >> 6;
    const int l15 = lane & 15;
    const int kg = lane >> 4;
    const float* offB = off0 + (size_t)b * 24 * HW;

    // ---- phase 1: intermediate 34x10 = 340 px, ids (wv*3+f)*16 + l15 ----
    f32x4 acc1[2][3];
#pragma unroll
    for (int m = 0; m < 2; ++m)
#pragma unroll
        for (int f = 0; f < 3; ++f) acc1[m][f] = {0.f, 0.f, 0.f, 0.f};

    int fgy[3], fgx[3], foff[3];
#pragma unroll
    for (int f = 0; f < 3; ++f) {
        int id = (wv * 3 + f) * 16 + l15;
        int rid = min(id, 339);
        int iy = rid / 34, ix = rid - iy * 34;
        fgy[f] = by0 - 1 + iy;
        fgx[f] = bx0 - 1 + ix;
        int cy = min(max(fgy[f], 0), HH - 1);
        int cx = min(max(fgx[f], 0), WW - 1);
        foff[f] = cy * WW + cx;
    }
    const unsigned short* w1l = w1p + (size_t)(l15 * 32 + kg * 8);

#pragma unroll 1
    for (int t = 0; t < 9; ++t) {
        const int k = (t % 3) * 3 + t / 3;
        const float* offx = offB + (size_t)(6 + 2 * k) * HW;
        const float* offy = offB + (size_t)(7 + 2 * k) * HW;
        bf16x8 afr[2];
#pragma unroll
        for (int m = 0; m < 2; ++m)
            afr[m] = *(const bf16x8*)(w1l + (size_t)(t * 32 + m * 16) * 32);

#pragma unroll
        for (int f = 0; f < 3; ++f) {
            if ((wv * 3 + f) * 16 >= 340) continue;   // wave-uniform dead-frag skip
            float dxv = offx[foff[f]] * 0.08f;
            float dyv = offy[foff[f]] * 0.08f;
            float pxf = (float)fgx[f] + dxv;
            float pyf = (float)fgy[f] + dyv;
            float x0f = floorf(pxf), y0f = floorf(pyf);
            float wx = pxf - x0f, wy = pyf - y0f;
            int tx0 = min(max((int)x0f - (bx0 - 2), 0), 34);
            int ty0 = min(max((int)y0f - (by0 - 2), 0), 10);
            bf16x8 bfr = lerp8<36>(xt, ty0 * 36 + tx0, wx, wy, kg);
#pragma unroll
            for (int m = 0; m < 2; ++m)
                acc1[m][f] = __builtin_amdgcn_mfma_f32_16x16x32_bf16(afr[m], bfr, acc1[m][f], 0, 0, 0);
        }
    }
    __syncthreads();   // all staging reads complete before overwrite

    // ---- write intermediate into the SAME LDS (ids < 340; pad to 352) ----
#pragma unroll
    for (int f = 0; f < 3; ++f) {
        int id = (wv * 3 + f) * 16 + l15;
        bool ok = ((unsigned)fgy[f] < HH) && ((unsigned)fgx[f] < WW) && (id < 340);
        int wid = min(id, 351);
#pragma unroll
        for (int m = 0; m < 2; ++m) {
            int cb = m * 16 + kg * 4;
            float v[4];
#pragma unroll
            for (int r = 0; r < 4; ++r)
                v[r] = ok ? fmaxf(acc1[m][f][r] + b1[cb + r], 0.f) : 0.f;
            uint2 o;
            o.x = cvtpk(v[0], v[1]);
            o.y = cvtpk(v[2], v[3]);
            *(uint2*)&xt[wid * CS + cb] = o;
        }
    }
    __syncthreads();

    // ---- phase 2: out 32x8, wave = row, sample intermediate (halo 1) ----
    f32x4 acc2[2][2];
#pragma unroll
    for (int m = 0; m < 2; ++m)
#pragma unroll
        for (int n = 0; n < 2; ++n) acc2[m][n] = {0.f, 0.f, 0.f, 0.f};

    const int py = by0 + wv;
    const unsigned short* w2l = w2p + (size_t)(l15 * 32 + kg * 8);

#pragma unroll 1
    for (int t = 0; t < 9; ++t) {
        const int k = (t % 3) * 3 + t / 3;
        const float* offx = offB + (size_t)(6 + 2 * k) * HW + (size_t)py * WW;
        const float* offy = offB + (size_t)(7 + 2 * k) * HW + (size_t)py * WW;
        bf16x8 afr[2];
#pragma unroll
        for (int m = 0; m < 2; ++m)
            afr[m] = *(const bf16x8*)(w2l + (size_t)(t * 32 + m * 16) * 32);

        bf16x8 bfr[2];
#pragma unroll
        for (int n = 0; n < 2; ++n) {
            const int pxi = bx0 + n * 16 + l15;
            float dxv = offx[pxi] * 0.08f;
            float dyv = offy[pxi] * 0.08f;
            float pxf = (float)pxi + dxv;
            float pyf = (float)py + dyv;
            float x0f = floorf(pxf), y0f = floorf(pyf);
            float wx = pxf - x0f, wy = pyf - y0f;
            int mx0 = min(max((int)x0f - (bx0 - 1), 0), 32);
            int my0 = min(max((int)y0f - (by0 - 1), 0), 8);
            bfr[n] = lerp8<34>(xt, my0 * 34 + mx0, wx, wy, kg);
        }
#pragma unroll
        for (int m = 0; m < 2; ++m)
#pragma unroll
            for (int n = 0; n < 2; ++n)
                acc2[m][n] = __builtin_amdgcn_mfma_f32_16x16x32_bf16(afr[m], bfr[n], acc2[m][n], 0, 0, 0);
    }

    // ---- epilogue: bias + residual (global, L2-hot) ----
    unsigned short* outb = out + (size_t)b * HW * 32;
#pragma unroll
    for (int n = 0; n < 2; ++n) {
        int gx = bx0 + n * 16 + l15;
        size_t pidx = ((size_t)py * WW + gx) * 32;
#pragma unroll
        for (int m = 0; m < 2; ++m) {
            int cb = m * 16 + kg * 4;
            float v[4];
#pragma unroll
            for (int r = 0; r < 4; ++r) v[r] = acc2[m][n][r] + b2[cb + r];
            uint2 rr = *(const uint2*)&inb[pidx + cb];
            v[0] += bflo(rr.x); v[1] += bfhi(rr.x);
            v[2] += bflo(rr.y); v[3] += bfhi(rr.y);
            uint2 o;
            o.x = cvtpk(v[0], v[1]);
            o.y = cvtpk(v[2], v[3]);
            *(uint2*)&outb[pidx + cb] = o;
        }
    }
}

// ---------------------------------------------------------------------------
// Final 3x3 conv 32->3, bf16 NHWC in, fp32 NCHW out.
// ---------------------------------------------------------------------------
__global__ __launch_bounds__(256) void conv3f(const unsigned short* __restrict__ in,
                                              const float* __restrict__ wgt,
                                              const float* __restrict__ bias,
                                              float* __restrict__ out) {
    __shared__ unsigned short xt[324 * 34];
    const int tid = threadIdx.x;
    const int lx = tid & 15, ly = tid >> 4;
    const int bx = blockIdx.x << 4, by = blockIdx.y << 4;
    const int b = blockIdx.z;

    const unsigned short* inb = in + (size_t)b * HW * 32;
    for (int idx = tid; idx < 324 * 8; idx += 256) {
        int hp = idx >> 3, sub = idx & 7;
        int hy = hp / 18, hx = hp - hy * 18;
        int gy = by + hy - 1, gx = bx + hx - 1;
        uint2 v = {0, 0};
        if (((unsigned)gy < HH) && ((unsigned)gx < WW))
            v = *(const uint2*)&inb[((size_t)gy * WW + gx) * 32 + sub * 4];
        *(uint2*)&xt[hp * 34 + sub * 4] = v;
    }
    __syncthreads();

    float a0 = bias[0], a1 = bias[1], a2 = bias[2];
#pragma unroll
    for (int ty = 0; ty < 3; ++ty) {
#pragma unroll
        for (int tx = 0; tx < 3; ++tx) {
            const unsigned short* row = &xt[((ly + ty) * 18 + lx + tx) * 34];
#pragma unroll 8
            for (int c = 0; c < 32; c += 2) {
                unsigned pv = *(const unsigned*)&row[c];
                float vl = bflo(pv), vh = bfhi(pv);
                const float* wl = wgt + (size_t)(c * 3 + ty) * 3 + tx;
                const float* whp = wgt + (size_t)((c + 1) * 3 + ty) * 3 + tx;
                a0 = fmaf(vl, wl[0], a0);          a0 = fmaf(vh, whp[0], a0);
                a1 = fmaf(vl, wl[32 * 9], a1);     a1 = fmaf(vh, whp[32 * 9], a1);
                a2 = fmaf(vl, wl[64 * 9], a2);     a2 = fmaf(vh, whp[64 * 9], a2);
            }
        }
    }
    const size_t o0 = ((size_t)b * 3) * HW + (size_t)(by + ly) * WW + bx + lx;
    out[o0] = a0;
    out[o0 + HW] = a1;
    out[o0 + 2 * HW] = a2;
}

extern "C" void kernel_launch(void* const* d_in, const int* in_sizes, int n_in,
                              void* d_out, int out_size, void* d_ws, size_t ws_size,
                              hipStream_t stream) {
    const float* x    = (const float*)d_in[0];
    const float* off0 = (const float*)d_in[1];
    const float* w12  = (const float*)d_in[2];
    const float* b12  = (const float*)d_in[3];
    const float* w13a = (const float*)d_in[4];
    const float* b13a = (const float*)d_in[5];
    const float* w13b = (const float*)d_in[6];
    const float* b13b = (const float*)d_in[7];
    const float* w14a = (const float*)d_in[8];
    const float* b14a = (const float*)d_in[9];
    const float* w14b = (const float*)d_in[10];
    const float* b14b = (const float*)d_in[11];
    const float* w15  = (const float*)d_in[12];
    const float* b15  = (const float*)d_in[13];
    const float* w50  = (const float*)d_in[14];
    const float* b50  = (const float*)d_in[15];
    const float* w51  = (const float*)d_in[16];
    const float* b51  = (const float*)d_in[17];
    const float* w60  = (const float*)d_in[18];
    const float* b60  = (const float*)d_in[19];
    const float* w61  = (const float*)d_in[20];
    const float* b61  = (const float*)d_in[21];
    const float* w24  = (const float*)d_in[22];
    const float* b24  = (const float*)d_in[23];

    // ws layout (ushort): A (2*HW*64) | B (2*HW*64; D,E alias) | packed weights
    unsigned short* A  = (unsigned short*)d_ws;
    unsigned short* Bb = A + (size_t)2 * HW * 64;
    unsigned short* D  = Bb;
    unsigned short* E  = Bb + (size_t)2 * HW * 32;
    unsigned short* wpk = Bb + (size_t)2 * HW * 64;
    const int SZ64 = 64 * 64 * 9;
    const int SZ32 = 32 * 64 * 9;
    const int SZD  = 32 * 32 * 9;
    unsigned short* p12  = wpk;
    unsigned short* p13a = p12 + SZ64;
    unsigned short* p13b = p13a + SZ64;
    unsigned short* p14a = p13b + SZ64;
    unsigned short* p14b = p14a + SZ64;
    unsigned short* p15  = p14b + SZ64;
    unsigned short* q50  = p15 + SZ32;
    unsigned short* q51  = q50 + SZD;
    unsigned short* q60  = q51 + SZD;
    unsigned short* q61  = q60 + SZD;
    float* out = (float*)d_out;

    prepack_all<<<dim3(144, 10), 256, 0, stream>>>(
        w12, w13a, w13b, w14a, w14b, w15, w50, w51, w60, w61,
        p12, p13a, p13b, p14a, p14b, p15, q50, q51, q60, q61);

    dim3 gm(WW / 32, HH / 4, 2);   // 8 x 64 x 2 = 1024 blocks
    dim3 gd(WW / 32, HH / 8, 2);   // dpair: 32x8 tile, 512 blocks, 512 thr
    dim3 gs(HH / 16, WW / 16, 2);

    convmfma<true,  64, 64, false, false><<<gm, 256, 0, stream>>>(x,  p12,  b12,  nullptr, A);
    convmfma<false, 64, 64, true,  false><<<gm, 256, 0, stream>>>(A,  p13a, b13a, nullptr, Bb);
    convmfma<false, 64, 64, false, true ><<<gm, 256, 0, stream>>>(Bb, p13b, b13b, A, A);
    convmfma<false, 64, 64, true,  false><<<gm, 256, 0, stream>>>(A,  p14a, b14a, nullptr, Bb);
    convmfma<false, 64, 64, false, true ><<<gm, 256, 0, stream>>>(Bb, p14b, b14b, A, A);
    convmfma<false, 64, 32, false, false><<<gm, 128, 0, stream>>>(A,  p15,  b15,  nullptr, D);

    dpair<<<gd, 512, 0, stream>>>(D, off0, q50, b50, q51, b51, E);
    dpair<<<gd, 512, 0, stream>>>(E, off0, q60, b60, q61, b61, D);
    conv3f<<<gs, 256, 0, stream>>>(D, w24, b24, out);
}

// Round 10
// 216.521 us; speedup vs baseline: 1.0923x; 1.0209x over previous
//
#include <hip/hip_runtime.h>

#define HH 256
#define WW 256
#define HW (HH * WW)

typedef float f32x4 __attribute__((ext_vector_type(4)));
typedef float f32x2 __attribute__((ext_vector_type(2)));
typedef short bf16x8 __attribute__((ext_vector_type(8)));

__device__ __forceinline__ unsigned short f2bf(float f) {
    union { float f; unsigned u; } v; v.f = f;
    unsigned r = v.u + 0x7fff + ((v.u >> 16) & 1);   // RNE
    return (unsigned short)(r >> 16);
}
__device__ __forceinline__ float bflo(unsigned u) {
    union { unsigned u; float f; } v; v.u = u << 16; return v.f;
}
__device__ __forceinline__ float bfhi(unsigned u) {
    union { unsigned u; float f; } v; v.u = u & 0xffff0000u; return v.f;
}
// one-instruction pack of 2 f32 -> 2 bf16 (RNE); no builtin on gfx950
__device__ __forceinline__ unsigned cvtpk(float lo, float hi) {
    unsigned r;
    asm("v_cvt_pk_bf16_f32 %0, %1, %2" : "=v"(r) : "v"(lo), "v"(hi));
    return r;
}
// packed 2xf32 ops (VOP3P, gfx90a+)
__device__ __forceinline__ f32x2 pkmul(f32x2 a, f32x2 b) {
    f32x2 d;
    asm("v_pk_mul_f32 %0, %1, %2" : "=v"(d) : "v"(a), "v"(b));
    return d;
}
__device__ __forceinline__ f32x2 pkfma(f32x2 a, f32x2 b, f32x2 c) {
    f32x2 d;
    asm("v_pk_fma_f32 %0, %1, %2, %3" : "=v"(d) : "v"(a), "v"(b), "v"(c));
    return d;
}
__device__ __forceinline__ f32x2 up2(unsigned u) {
    f32x2 r;
    union { unsigned u; float f; } lo, hi;
    lo.u = u << 16; hi.u = u & 0xffff0000u;
    r[0] = lo.f; r[1] = hi.f;
    return r;
}

// bilinear lerp of 8 bf16 channels from a pixel-major LDS tile (row width W px,
// row stride 40 ushorts), corners (lp, lp+1, lp+W, lp+W+1), packed-f32 math.
template <int W>
__device__ __forceinline__ bf16x8 lerp8(const unsigned short* __restrict__ tile,
                                        int lp, float wx, float wy, int kg) {
    const unsigned short* p = tile + lp * 40 + kg * 8;
    uint4 a00 = *(const uint4*)p;
    uint4 a01 = *(const uint4*)(p + 40);
    uint4 a10 = *(const uint4*)(p + W * 40);
    uint4 a11 = *(const uint4*)(p + W * 40 + 40);
    float omx = 1.f - wx, omy = 1.f - wy;
    float s00 = omy * omx, s01 = omy * wx, s10 = wy * omx, s11 = wy * wx;
    f32x2 w00p = {s00, s00}, w01p = {s01, s01}, w10p = {s10, s10}, w11p = {s11, s11};
    unsigned c00[4] = {a00.x, a00.y, a00.z, a00.w};
    unsigned c01[4] = {a01.x, a01.y, a01.z, a01.w};
    unsigned c10[4] = {a10.x, a10.y, a10.z, a10.w};
    unsigned c11[4] = {a11.x, a11.y, a11.z, a11.w};
    union { bf16x8 v; unsigned u[4]; } ur;
#pragma unroll
    for (int j = 0; j < 4; ++j) {
        f32x2 s = pkmul(w00p, up2(c00[j]));
        s = pkfma(w01p, up2(c01[j]), s);
        s = pkfma(w10p, up2(c10[j]), s);
        s = pkfma(w11p, up2(c11[j]), s);
        ur.u[j] = cvtpk(s[0], s[1]);
    }
    return ur.v;
}

// ---------------------------------------------------------------------------
// Merged weight prepack: fp32 OIHW -> bf16 [tap][kc][cout][k32] for all 10
// conv layers (blockIdx.y = layer). Tap t holds spatial w[o][ci][t/3][t%3].
// ---------------------------------------------------------------------------
__global__ void prepack_all(
    const float* w0, const float* w1, const float* w2, const float* w3,
    const float* w4, const float* w5, const float* w6, const float* w7,
    const float* w8, const float* w9,
    unsigned short* d0, unsigned short* d1, unsigned short* d2,
    unsigned short* d3, unsigned short* d4, unsigned short* d5,
    unsigned short* d6, unsigned short* d7, unsigned short* d8,
    unsigned short* d9) {
    const int L = blockIdx.y;
    const float* w; unsigned short* dst; int COUT, CIN;
    switch (L) {
        case 0: w = w0; dst = d0; COUT = 64; CIN = 64; break;
        case 1: w = w1; dst = d1; COUT = 64; CIN = 64; break;
        case 2: w = w2; dst = d2; COUT = 64; CIN = 64; break;
        case 3: w = w3; dst = d3; COUT = 64; CIN = 64; break;
        case 4: w = w4; dst = d4; COUT = 64; CIN = 64; break;
        case 5: w = w5; dst = d5; COUT = 32; CIN = 64; break;
        case 6: w = w6; dst = d6; COUT = 32; CIN = 32; break;
        case 7: w = w7; dst = d7; COUT = 32; CIN = 32; break;
        case 8: w = w8; dst = d8; COUT = 32; CIN = 32; break;
        default: w = w9; dst = d9; COUT = 32; CIN = 32; break;
    }
    int n = COUT * CIN * 9;
    int i = blockIdx.x * 256 + threadIdx.x;
    if (i >= n) return;
    int q = i & 31;
    int rest = i >> 5;
    int o = rest % COUT;
    int rest2 = rest / COUT;
    int KC = CIN >> 5;
    int kc = rest2 % KC;
    int t = rest2 / KC;
    int cin = kc * 32 + q;
    float v = w[((o * CIN + cin) * 3 + t / 3) * 3 + (t % 3)];
    dst[i] = f2bf(v);
}

// ---------------------------------------------------------------------------
// 3x3 conv via bf16 MFMA implicit GEMM (tile 32x4, halo 34x6, wave = 32 cout
// x 64 px, grid 1024 blocks). Activations bf16 NHWC (first layer fp32 NCHW).
// Out bf16 NHWC; fused bias/ReLU/residual.
// ---------------------------------------------------------------------------
template <bool SRCF32, int CIN, int COUT, bool RELU, bool ADDRES>
__global__ __launch_bounds__((COUT / 32) * 128) void convmfma(
    const void* __restrict__ in_, const unsigned short* __restrict__ wp,
    const float* __restrict__ bias, const unsigned short* __restrict__ res,
    unsigned short* __restrict__ out) {
    constexpr int KC = CIN / 32;
    constexpr int WM = COUT / 32;
    constexpr int NT = WM * 128;
    constexpr int CSTR = (CIN == 64) ? 72 : 40;
    __shared__ unsigned short xt[204 * CSTR];

    const int tid = threadIdx.x;
    const int b = blockIdx.z;
    const int bx0 = blockIdx.x * 32;
    const int by0 = blockIdx.y * 4;

    if (SRCF32) {
        const float* inb = (const float*)in_ + (size_t)b * CIN * HW;
        for (int hp = tid; hp < 204; hp += NT) {
            int hy = hp / 34, hx = hp - hy * 34;
            int gy = by0 + hy - 1, gx = bx0 + hx - 1;
            bool ok = ((unsigned)gy < HH) && ((unsigned)gx < WW);
            const float* src = inb + ((size_t)gy * WW + gx);
            unsigned* dstp = (unsigned*)&xt[hp * CSTR];
#pragma unroll 4
            for (int c = 0; c < CIN; c += 2) {
                float v0 = ok ? src[(size_t)c * HW] : 0.f;
                float v1 = ok ? src[(size_t)(c + 1) * HW] : 0.f;
                dstp[c >> 1] = cvtpk(v0, v1);
            }
        }
    } else {
        const unsigned short* inb = (const unsigned short*)in_ + (size_t)b * HW * CIN;
        constexpr int CH = CIN / 8;
        for (int idx = tid; idx < 204 * CH; idx += NT) {
            int hp = idx / CH, sub = idx - hp * CH;
            int hy = hp / 34, hx = hp - hy * 34;
            int gy = by0 + hy - 1, gx = bx0 + hx - 1;
            uint4 v = {0, 0, 0, 0};
            if (((unsigned)gy < HH) && ((unsigned)gx < WW))
                v = *(const uint4*)&inb[((size_t)gy * WW + gx) * CIN + sub * 8];
            *(uint4*)&xt[hp * CSTR + sub * 8] = v;
        }
    }
    __syncthreads();

    const int lane = tid & 63;
    const int wv = tid >> 6;
    const int wm = (WM == 2) ? (wv & 1) : 0;
    const int wn = (WM == 2) ? (wv >> 1) : wv;
    const int l15 = lane & 15;
    const int kg = lane >> 4;

    f32x4 acc[2][4];
#pragma unroll
    for (int m = 0; m < 2; ++m)
#pragma unroll
        for (int n = 0; n < 4; ++n) acc[m][n] = {0.f, 0.f, 0.f, 0.f};

    int hbase[4];
#pragma unroll
    for (int n = 0; n < 4; ++n) {
        int p = wn * 64 + n * 16 + l15;
        hbase[n] = (p >> 5) * 34 + (p & 31);
    }

    const unsigned short* wlane = wp + ((size_t)(wm * 32 + l15) * 4 + kg) * 8;

#pragma unroll
    for (int t = 0; t < 9; ++t) {
        bf16x8 afr[2][KC];
#pragma unroll
        for (int kc = 0; kc < KC; ++kc)
#pragma unroll
            for (int m = 0; m < 2; ++m)
                afr[m][kc] = *(const bf16x8*)(wlane + ((size_t)(t * KC + kc) * COUT + m * 16) * 32);

        const int hoff = (t / 3) * 34 + (t % 3);
#pragma unroll
        for (int kc = 0; kc < KC; ++kc) {
            bf16x8 bfr[4];
#pragma unroll
            for (int n = 0; n < 4; ++n)
                bfr[n] = *(const bf16x8*)&xt[(hbase[n] + hoff) * CSTR + kc * 32 + kg * 8];
#pragma unroll
            for (int m = 0; m < 2; ++m)
#pragma unroll
                for (int n = 0; n < 4; ++n)
                    acc[m][n] = __builtin_amdgcn_mfma_f32_16x16x32_bf16(afr[m][kc], bfr[n], acc[m][n], 0, 0, 0);
        }
    }

    const size_t pixbase = (size_t)b * HW;
#pragma unroll
    for (int m = 0; m < 2; ++m) {
#pragma unroll
        for (int n = 0; n < 4; ++n) {
            int p = wn * 64 + n * 16 + l15;
            int gy = by0 + (p >> 5), gx = bx0 + (p & 31);
            size_t pidx = (pixbase + (size_t)gy * WW + gx) * COUT;
            int cb = wm * 32 + m * 16 + kg * 4;
            float v[4];
#pragma unroll
            for (int r = 0; r < 4; ++r) {
                v[r] = acc[m][n][r] + bias[cb + r];
                if (RELU) v[r] = fmaxf(v[r], 0.f);
            }
            if (ADDRES) {
                uint2 rr = *(const uint2*)&res[pidx + cb];
                v[0] += bflo(rr.x); v[1] += bfhi(rr.x);
                v[2] += bflo(rr.y); v[3] += bfhi(rr.y);
            }
            uint2 o;
            o.x = cvtpk(v[0], v[1]);
            o.y = cvtpk(v[2], v[3]);
            *(uint2*)&out[pidx + cb] = o;
        }
    }
}

// ---------------------------------------------------------------------------
// Fused deformable pair (32ch): out = in + dconv_w2(relu(dconv_w1(in))).
// Round-7 structure: tile 32x8 out, staged input 36x12 (halo 2), SEPARATE
// intermediate region 34x10 (halo 1) -> only 2 barriers (phase-1 MFMAs
// overlap the mid writes across waves). Taps cancel with modulation grid;
// |disp| < 1 px on this data. Packed-f32 lerp + cross-tap offset prefetch
// (tap t issues tap t+1's offset loads before the lerp work, hiding global
// latency under VALU+MFMA).
// ---------------------------------------------------------------------------
__global__ __launch_bounds__(512) void dpair(
    const unsigned short* __restrict__ in, const float* __restrict__ off0,
    const unsigned short* __restrict__ w1p, const float* __restrict__ b1,
    const unsigned short* __restrict__ w2p, const float* __restrict__ b2,
    unsigned short* __restrict__ out) {
    constexpr int CS = 40;
    constexpr int MIDB = 432 * CS;
    __shared__ unsigned short xt[(432 + 352) * CS];

    const int tid = threadIdx.x;
    const int b = blockIdx.z;
    const int bx0 = blockIdx.x * 32;
    const int by0 = blockIdx.y * 8;

    const unsigned short* inb = in + (size_t)b * HW * 32;
    for (int idx = tid; idx < 432 * 4; idx += 512) {
        int hp = idx >> 2, sub = idx & 3;
        int hy = hp / 36, hx = hp - hy * 36;
        int gy = by0 + hy - 2, gx = bx0 + hx - 2;
        uint4 v = {0, 0, 0, 0};
        if (((unsigned)gy < HH) && ((unsigned)gx < WW))
            v = *(const uint4*)&inb[((size_t)gy * WW + gx) * 32 + sub * 8];
        *(uint4*)&xt[hp * CS + sub * 8] = v;
    }
    __syncthreads();

    const int lane = tid & 63;
    const int wv = tid >> 6;
    const int l15 = lane & 15;
    const int kg = lane >> 4;
    const float* offB = off0 + (size_t)b * 24 * HW;

    // ---- phase 1: intermediate 34x10 = 340 px, ids (wv*3+f)*16 + l15 ----
    f32x4 acc1[2][3];
#pragma unroll
    for (int m = 0; m < 2; ++m)
#pragma unroll
        for (int f = 0; f < 3; ++f) acc1[m][f] = {0.f, 0.f, 0.f, 0.f};

    int fgy[3], fgx[3], foff[3];
#pragma unroll
    for (int f = 0; f < 3; ++f) {
        int id = (wv * 3 + f) * 16 + l15;
        int rid = min(id, 339);
        int iy = rid / 34, ix = rid - iy * 34;
        fgy[f] = by0 - 1 + iy;
        fgx[f] = bx0 - 1 + ix;
        int cy = min(max(fgy[f], 0), HH - 1);
        int cx = min(max(fgx[f], 0), WW - 1);
        foff[f] = cy * WW + cx;
    }
    const unsigned short* w1l = w1p + (size_t)(l15 * 32 + kg * 8);

    float cdx[3], cdy[3];
#pragma unroll
    for (int f = 0; f < 3; ++f) {           // tap t=0 -> k=0 -> chans 6,7
        cdx[f] = offB[(size_t)6 * HW + foff[f]];
        cdy[f] = offB[(size_t)7 * HW + foff[f]];
    }

#pragma unroll 1
    for (int t = 0; t < 9; ++t) {
        float ndx[3], ndy[3];
        if (t < 8) {                         // prefetch tap t+1 offsets
            const int kn = ((t + 1) % 3) * 3 + (t + 1) / 3;
            const float* nx = offB + (size_t)(6 + 2 * kn) * HW;
            const float* ny = offB + (size_t)(7 + 2 * kn) * HW;
#pragma unroll
            for (int f = 0; f < 3; ++f) { ndx[f] = nx[foff[f]]; ndy[f] = ny[foff[f]]; }
        }
        bf16x8 afr[2];
#pragma unroll
        for (int m = 0; m < 2; ++m)
            afr[m] = *(const bf16x8*)(w1l + (size_t)(t * 32 + m * 16) * 32);

#pragma unroll
        for (int f = 0; f < 3; ++f) {
            if ((wv * 3 + f) * 16 >= 340) continue;   // wave-uniform dead-frag skip
            float dxv = cdx[f] * 0.08f;
            float dyv = cdy[f] * 0.08f;
            float pxf = (float)fgx[f] + dxv;
            float pyf = (float)fgy[f] + dyv;
            float x0f = floorf(pxf), y0f = floorf(pyf);
            float wx = pxf - x0f, wy = pyf - y0f;
            int tx0 = min(max((int)x0f - (bx0 - 2), 0), 34);
            int ty0 = min(max((int)y0f - (by0 - 2), 0), 10);
            bf16x8 bfr = lerp8<36>(xt, ty0 * 36 + tx0, wx, wy, kg);
#pragma unroll
            for (int m = 0; m < 2; ++m)
                acc1[m][f] = __builtin_amdgcn_mfma_f32_16x16x32_bf16(afr[m], bfr, acc1[m][f], 0, 0, 0);
        }
        if (t < 8) {
#pragma unroll
            for (int f = 0; f < 3; ++f) { cdx[f] = ndx[f]; cdy[f] = ndy[f]; }
        }
    }

    // ---- write intermediate to SEPARATE region (no barrier needed first) ----
#pragma unroll
    for (int f = 0; f < 3; ++f) {
        int id = (wv * 3 + f) * 16 + l15;
        bool ok = ((unsigned)fgy[f] < HH) && ((unsigned)fgx[f] < WW) && (id < 340);
        int wid = min(id, 351);
#pragma unroll
        for (int m = 0; m < 2; ++m) {
            int cb = m * 16 + kg * 4;
            float v[4];
#pragma unroll
            for (int r = 0; r < 4; ++r)
                v[r] = ok ? fmaxf(acc1[m][f][r] + b1[cb + r], 0.f) : 0.f;
            uint2 o;
            o.x = cvtpk(v[0], v[1]);
            o.y = cvtpk(v[2], v[3]);
            *(uint2*)&xt[MIDB + wid * CS + cb] = o;
        }
    }
    __syncthreads();

    // ---- phase 2: out 32x8, wave = row, sample intermediate (halo 1) ----
    f32x4 acc2[2][2];
#pragma unroll
    for (int m = 0; m < 2; ++m)
#pragma unroll
        for (int n = 0; n < 2; ++n) acc2[m][n] = {0.f, 0.f, 0.f, 0.f};

    const int py = by0 + wv;
    const unsigned short* w2l = w2p + (size_t)(l15 * 32 + kg * 8);
    const int prow = py * WW;
    const int pxi[2] = {bx0 + l15, bx0 + 16 + l15};

    float cdx2[2], cdy2[2];
#pragma unroll
    for (int n = 0; n < 2; ++n) {            // tap t=0 -> k=0
        cdx2[n] = offB[(size_t)6 * HW + prow + pxi[n]];
        cdy2[n] = offB[(size_t)7 * HW + prow + pxi[n]];
    }

#pragma unroll 1
    for (int t = 0; t < 9; ++t) {
        float ndx[2], ndy[2];
        if (t < 8) {
            const int kn = ((t + 1) % 3) * 3 + (t + 1) / 3;
            const float* nx = offB + (size_t)(6 + 2 * kn) * HW + prow;
            const float* ny = offB + (size_t)(7 + 2 * kn) * HW + prow;
#pragma unroll
            for (int n = 0; n < 2; ++n) { ndx[n] = nx[pxi[n]]; ndy[n] = ny[pxi[n]]; }
        }
        bf16x8 afr[2];
#pragma unroll
        for (int m = 0; m < 2; ++m)
            afr[m] = *(const bf16x8*)(w2l + (size_t)(t * 32 + m * 16) * 32);

        bf16x8 bfr[2];
#pragma unroll
        for (int n = 0; n < 2; ++n) {
            float dxv = cdx2[n] * 0.08f;
            float dyv = cdy2[n] * 0.08f;
            float pxf = (float)pxi[n] + dxv;
            float pyf = (float)py + dyv;
            float x0f = floorf(pxf), y0f = floorf(pyf);
            float wx = pxf - x0f, wy = pyf - y0f;
            int mx0 = min(max((int)x0f - (bx0 - 1), 0), 32);
            int my0 = min(max((int)y0f - (by0 - 1), 0), 8);
            bfr[n] = lerp8<34>(xt + MIDB, my0 * 34 + mx0, wx, wy, kg);
        }
#pragma unroll
        for (int m = 0; m < 2; ++m)
#pragma unroll
            for (int n = 0; n < 2; ++n)
                acc2[m][n] = __builtin_amdgcn_mfma_f32_16x16x32_bf16(afr[m], bfr[n], acc2[m][n], 0, 0, 0);
        if (t < 8) {
#pragma unroll
            for (int n = 0; n < 2; ++n) { cdx2[n] = ndx[n]; cdy2[n] = ndy[n]; }
        }
    }

    // ---- epilogue: bias + residual (global, L2-hot) ----
    unsigned short* outb = out + (size_t)b * HW * 32;
#pragma unroll
    for (int n = 0; n < 2; ++n) {
        size_t pidx = ((size_t)prow + pxi[n]) * 32;
#pragma unroll
        for (int m = 0; m < 2; ++m) {
            int cb = m * 16 + kg * 4;
            float v[4];
#pragma unroll
            for (int r = 0; r < 4; ++r) v[r] = acc2[m][n][r] + b2[cb + r];
            uint2 rr = *(const uint2*)&inb[pidx + cb];
            v[0] += bflo(rr.x); v[1] += bfhi(rr.x);
            v[2] += bflo(rr.y); v[3] += bfhi(rr.y);
            uint2 o;
            o.x = cvtpk(v[0], v[1]);
            o.y = cvtpk(v[2], v[3]);
            *(uint2*)&outb[pidx + cb] = o;
        }
    }
}

// ---------------------------------------------------------------------------
// Final 3x3 conv 32->3, bf16 NHWC in, fp32 NCHW out.
// ---------------------------------------------------------------------------
__global__ __launch_bounds__(256) void conv3f(const unsigned short* __restrict__ in,
                                              const float* __restrict__ wgt,
                                              const float* __restrict__ bias,
                                              float* __restrict__ out) {
    __shared__ unsigned short xt[324 * 34];
    const int tid = threadIdx.x;
    const int lx = tid & 15, ly = tid >> 4;
    const int bx = blockIdx.x << 4, by = blockIdx.y << 4;
    const int b = blockIdx.z;

    const unsigned short* inb = in + (size_t)b * HW * 32;
    for (int idx = tid; idx < 324 * 8; idx += 256) {
        int hp = idx >> 3, sub = idx & 7;
        int hy = hp / 18, hx = hp - hy * 18;
        int gy = by + hy - 1, gx = bx + hx - 1;
        uint2 v = {0, 0};
        if (((unsigned)gy < HH) && ((unsigned)gx < WW))
            v = *(const uint2*)&inb[((size_t)gy * WW + gx) * 32 + sub * 4];
        *(uint2*)&xt[hp * 34 + sub * 4] = v;
    }
    __syncthreads();

    float a0 = bias[0], a1 = bias[1], a2 = bias[2];
#pragma unroll
    for (int ty = 0; ty < 3; ++ty) {
#pragma unroll
        for (int tx = 0; tx < 3; ++tx) {
            const unsigned short* row = &xt[((ly + ty) * 18 + lx + tx) * 34];
#pragma unroll 8
            for (int c = 0; c < 32; c += 2) {
                unsigned pv = *(const unsigned*)&row[c];
                float vl = bflo(pv), vh = bfhi(pv);
                const float* wl = wgt + (size_t)(c * 3 + ty) * 3 + tx;
                const float* whp = wgt + (size_t)((c + 1) * 3 + ty) * 3 + tx;
                a0 = fmaf(vl, wl[0], a0);          a0 = fmaf(vh, whp[0], a0);
                a1 = fmaf(vl, wl[32 * 9], a1);     a1 = fmaf(vh, whp[32 * 9], a1);
                a2 = fmaf(vl, wl[64 * 9], a2);     a2 = fmaf(vh, whp[64 * 9], a2);
            }
        }
    }
    const size_t o0 = ((size_t)b * 3) * HW + (size_t)(by + ly) * WW + bx + lx;
    out[o0] = a0;
    out[o0 + HW] = a1;
    out[o0 + 2 * HW] = a2;
}

extern "C" void kernel_launch(void* const* d_in, const int* in_sizes, int n_in,
                              void* d_out, int out_size, void* d_ws, size_t ws_size,
                              hipStream_t stream) {
    const float* x    = (const float*)d_in[0];
    const float* off0 = (const float*)d_in[1];
    const float* w12  = (const float*)d_in[2];
    const float* b12  = (const float*)d_in[3];
    const float* w13a = (const float*)d_in[4];
    const float* b13a = (const float*)d_in[5];
    const float* w13b = (const float*)d_in[6];
    const float* b13b = (const float*)d_in[7];
    const float* w14a = (const float*)d_in[8];
    const float* b14a = (const float*)d_in[9];
    const float* w14b = (const float*)d_in[10];
    const float* b14b = (const float*)d_in[11];
    const float* w15  = (const float*)d_in[12];
    const float* b15  = (const float*)d_in[13];
    const float* w50  = (const float*)d_in[14];
    const float* b50  = (const float*)d_in[15];
    const float* w51  = (const float*)d_in[16];
    const float* b51  = (const float*)d_in[17];
    const float* w60  = (const float*)d_in[18];
    const float* b60  = (const float*)d_in[19];
    const float* w61  = (const float*)d_in[20];
    const float* b61  = (const float*)d_in[21];
    const float* w24  = (const float*)d_in[22];
    const float* b24  = (const float*)d_in[23];

    // ws layout (ushort): A (2*HW*64) | B (2*HW*64; D,E alias) | packed weights
    unsigned short* A  = (unsigned short*)d_ws;
    unsigned short* Bb = A + (size_t)2 * HW * 64;
    unsigned short* D  = Bb;
    unsigned short* E  = Bb + (size_t)2 * HW * 32;
    unsigned short* wpk = Bb + (size_t)2 * HW * 64;
    const int SZ64 = 64 * 64 * 9;
    const int SZ32 = 32 * 64 * 9;
    const int SZD  = 32 * 32 * 9;
    unsigned short* p12  = wpk;
    unsigned short* p13a = p12 + SZ64;
    unsigned short* p13b = p13a + SZ64;
    unsigned short* p14a = p13b + SZ64;
    unsigned short* p14b = p14a + SZ64;
    unsigned short* p15  = p14b + SZ64;
    unsigned short* q50  = p15 + SZ32;
    unsigned short* q51  = q50 + SZD;
    unsigned short* q60  = q51 + SZD;
    unsigned short* q61  = q60 + SZD;
    float* out = (float*)d_out;

    prepack_all<<<dim3(144, 10), 256, 0, stream>>>(
        w12, w13a, w13b, w14a, w14b, w15, w50, w51, w60, w61,
        p12, p13a, p13b, p14a, p14b, p15, q50, q51, q60, q61);

    dim3 gm(WW / 32, HH / 4, 2);   // 8 x 64 x 2 = 1024 blocks
    dim3 gd(WW / 32, HH / 8, 2);   // dpair: 32x8 tile, 512 blocks, 512 thr
    dim3 gs(HH / 16, WW / 16, 2);

    convmfma<true,  64, 64, false, false><<<gm, 256, 0, stream>>>(x,  p12,  b12,  nullptr, A);
    convmfma<false, 64, 64, true,  false><<<gm, 256, 0, stream>>>(A,  p13a, b13a, nullptr, Bb);
    convmfma<false, 64, 64, false, true ><<<gm, 256, 0, stream>>>(Bb, p13b, b13b, A, A);
    convmfma<false, 64, 64, true,  false><<<gm, 256, 0, stream>>>(A,  p14a, b14a, nullptr, Bb);
    convmfma<false, 64, 64, false, true ><<<gm, 256, 0, stream>>>(Bb, p14b, b14b, A, A);
    convmfma<false, 64, 32, false, false><<<gm, 128, 0, stream>>>(A,  p15,  b15,  nullptr, D);

    dpair<<<gd, 512, 0, stream>>>(D, off0, q50, b50, q51, b51, E);
    dpair<<<gd, 512, 0, stream>>>(E, off0, q60, b60, q61, b61, D);
    conv3f<<<gs, 256, 0, stream>>>(D, w24, b24, out);
}